// Round 5
// baseline (386.770 us; speedup 1.0000x reference)
//
#include <hip/hip_runtime.h>
#include <hip/hip_fp16.h>

// Fused 8-step diffusion, v6: v5 structure + correct launch-bounds (the
// single change), finally testing the streaming-fetch theory un-spilled.
//
// v5 post-mortem: VGPR_Count=64, WRITE_SIZE=184MB (168MB scratch spill).
// Allocation model now consistent across v1/v2/v4/v5: hipcc treats the
// occupancy target as min BLOCKS/CU (CUDA semantics), default 2:
//   (512)    -> 2x8 =16 waves/CU -> cap 128 (v1:120, v4:84, clean)
//   (512,4)  -> 4x8 =32 waves/CU -> cap  64 (v2: spill)
//   (1024)   -> 2x16=32 waves/CU -> cap  64 (v5: spill)
// This kernel needs ~110 live VGPRs -> declare (1024, 1): 16 waves/CU,
// 4 waves/EU, cap 128. One block/CU resident, 16 waves for latency hiding.
//
// Structure (unchanged from v5):
//  - ONE block per (n,c) plane: 256 blocks x 1024 threads. Thread = 4 rows
//    x 4 cols (rg=tid>>5 in 0..31, quad=tid&31). NO halo: compulsory-only
//    fetch (151MB wgt + 17MB x), plane edges are true zeros.
//  - k-OUTER / p-inner weight loads: per tap, each wave issues 4 dwordx4
//    covering contiguous 4KB; 16 waves sweep the 64KB tap plane; block's
//    DRAM footprint = one sequential 589KB run. Taps packed fp16
//    UNNORMALIZED, fp32 sums inline; post-pass applies 1/sum|w|.
//  - Step loop: two-barrier boundary exchange (v3's single-barrier raced),
//    NRG=32, LDS 32KB, fp32 accumulate.

constexpr int H = 128, W = 128, PLANE = H * W;
constexpr int NSTEP = 8;
constexpr int RPT  = 4;            // rows per thread (128 rows / 32 rg)
constexpr int NRG  = 32;

// 6-wide column window (cols j0-1 .. j0+4) from a float4 row segment
#define MKWIN(D, V) do {                                                     \
    (D)[1] = (V).x; (D)[2] = (V).y; (D)[3] = (V).z; (D)[4] = (V).w;          \
    float _l = __shfl_up((V).w, 1);                                          \
    float _r = __shfl_down((V).x, 1);                                        \
    (D)[0] = (quad == 0)  ? 0.f : _l;                                        \
    (D)[5] = (quad == 31) ? 0.f : _r;                                        \
} while (0)

__global__ __launch_bounds__(1024, 1)
void diff_fused(const float* __restrict__ xin,
                const float* __restrict__ wgt,
                float* __restrict__ out)
{
    __shared__ float ldsT[NRG][W];      // each rg's top row    (16 KB)
    __shared__ float ldsB[NRG][W];      // each rg's bottom row (16 KB)

    const int tid   = threadIdx.x;
    const int quad  = tid & 31;         // cols 4q..4q+3
    const int rg    = tid >> 5;         // 0..31
    const int j0    = quad * 4;
    const int r0    = rg * RPT;         // this thread's first row (0..124)
    const size_t pbase = (size_t)blockIdx.x * PLANE;

    const float* __restrict__ xp = xin + pbase;
    const float* __restrict__ wb = wgt + pbase * 9;

    // ---- weights: k-outer streaming load, pack |.| fp16 unnormalized,
    //      accumulate fp32 tap-sums; normalize in a post-pass ----
    __half2 wh[RPT][9][2];              // 72 VGPRs (packed |w|, then normalized)
    float s[RPT][4];
    #pragma unroll
    for (int p = 0; p < RPT; ++p) { s[p][0] = s[p][1] = s[p][2] = s[p][3] = 0.f; }

    #pragma unroll
    for (int k = 0; k < 9; ++k) {
        const float* wk = wb + (size_t)k * PLANE + r0 * W + j0;
        float4 v[RPT];
        #pragma unroll
        for (int p = 0; p < RPT; ++p)     // 4 back-to-back dwordx4: 4KB/wave
            v[p] = *reinterpret_cast<const float4*>(wk + p * W);
        #pragma unroll
        for (int p = 0; p < RPT; ++p) {
            const float a0 = fabsf(v[p].x), a1 = fabsf(v[p].y);
            const float a2 = fabsf(v[p].z), a3 = fabsf(v[p].w);
            s[p][0] += a0; s[p][1] += a1; s[p][2] += a2; s[p][3] += a3;
            wh[p][k][0] = __halves2half2(__float2half_rn(a0), __float2half_rn(a1));
            wh[p][k][1] = __halves2half2(__float2half_rn(a2), __float2half_rn(a3));
        }
    }
    // normalization post-pass: unpack, scale by 1/sum, repack
    #pragma unroll
    for (int p = 0; p < RPT; ++p) {
        const float i0 = 1.f / s[p][0], i1 = 1.f / s[p][1];
        const float i2 = 1.f / s[p][2], i3 = 1.f / s[p][3];
        #pragma unroll
        for (int k = 0; k < 9; ++k) {
            wh[p][k][0] = __halves2half2(
                __float2half_rn(__low2float (wh[p][k][0]) * i0),
                __float2half_rn(__high2float(wh[p][k][0]) * i1));
            wh[p][k][1] = __halves2half2(
                __float2half_rn(__low2float (wh[p][k][1]) * i2),
                __float2half_rn(__high2float(wh[p][k][1]) * i3));
        }
    }

    // ---- x rows into registers ----
    float4 xr[RPT];
    #pragma unroll
    for (int p = 0; p < RPT; ++p)
        xr[p] = *reinterpret_cast<const float4*>(xp + (r0 + p) * W + j0);

    // ---- 8 fused steps, zero global traffic, two barriers/step ----
    #pragma unroll 1
    for (int st = 0; st < NSTEP; ++st) {
        *reinterpret_cast<float4*>(&ldsT[rg][j0]) = xr[0];
        *reinterpret_cast<float4*>(&ldsB[rg][j0]) = xr[RPT - 1];
        __syncthreads();
        float4 up = make_float4(0.f, 0.f, 0.f, 0.f);   // row r0-1 (true 0 at rg=0)
        float4 dn = make_float4(0.f, 0.f, 0.f, 0.f);   // row r0+4 (true 0 at rg=31)
        if (rg > 0)       up = *reinterpret_cast<const float4*>(&ldsB[rg - 1][j0]);
        if (rg < NRG - 1) dn = *reinterpret_cast<const float4*>(&ldsT[rg + 1][j0]);
        __syncthreads();   // reads done before next step's writes

        float win[3][6];
        MKWIN(win[0], up);       // input row r0-1
        MKWIN(win[1], xr[0]);    // input row r0
        #pragma unroll
        for (int p = 0; p < RPT; ++p) {
            if (p < RPT - 1) { MKWIN(win[(p + 2) % 3], xr[p + 1]); }
            else             { MKWIN(win[(p + 2) % 3], dn); }
            float a0 = 0.f, a1 = 0.f, a2 = 0.f, a3 = 0.f;
            #pragma unroll
            for (int di = 0; di < 3; ++di) {
                #pragma unroll
                for (int dj = 0; dj < 3; ++dj) {
                    const int k = di * 3 + dj;
                    const __half2 w0 = wh[p][k][0];
                    const __half2 w1 = wh[p][k][1];
                    a0 = fmaf(__low2float (w0), win[(p + di) % 3][dj + 0], a0);
                    a1 = fmaf(__high2float(w0), win[(p + di) % 3][dj + 1], a1);
                    a2 = fmaf(__low2float (w1), win[(p + di) % 3][dj + 2], a2);
                    a3 = fmaf(__high2float(w1), win[(p + di) % 3][dj + 3], a3);
                }
            }
            xr[p] = make_float4(a0, a1, a2, a3);
        }
    }

    // ---- store all owned rows (coalesced float4, full plane) ----
    float* __restrict__ op = out + pbase;
    #pragma unroll
    for (int p = 0; p < RPT; ++p)
        *reinterpret_cast<float4*>(op + (r0 + p) * W + j0) = xr[p];
}

extern "C" void kernel_launch(void* const* d_in, const int* in_sizes, int n_in,
                              void* d_out, int out_size, void* d_ws, size_t ws_size,
                              hipStream_t stream)
{
    const float* x = (const float*)d_in[0];
    const float* w = (const float*)d_in[1];
    float* out = (float*)d_out;
    (void)d_ws; (void)ws_size; (void)in_sizes; (void)n_in; (void)out_size;

    // 256 blocks = 1 per (n,c) plane, 1024 threads (16 waves)
    diff_fused<<<dim3(4 * 64), dim3(1024), 0, stream>>>(x, w, out);
}

// Round 6
// 319.462 us; speedup vs baseline: 1.2107x; 1.2107x over previous
//
#include <hip/hip_runtime.h>
#include <hip/hip_fp16.h>

// Fused 8-step diffusion, v7: ATTRIBUTION ROUND (v4 + duplicated weight phase).
//
// After 6 rounds: every structural theory (gen-pipelining, streaming order,
// allocator semantics) missed. Proven facts: all variants converge to
// ~2.0-2.4 TB/s effective fetch regardless of structure; VALU<=20%; step-loop
// arithmetic estimates ~10us of 127. Missing: the load-phase vs step-phase
// time split, and the warm-cache service rate.
//
// This kernel = v4 with the weight load+normalize executed TWICE (idempotent:
// pass 2 overwrites with identical values). asm pins on pass-1 results +
// memory clobber prevent DCE/CSE (guide rule #17), so pass 2 re-issues all
// 221KB/block of loads -- guaranteed L2/L3-warm.
//   dur(v7) - dur(v4=127us) = X = load-phase cost AND warm-hit BW readout:
//   X>=80us -> warm-hit ceiling ~2.3TB/s -> optimize BYTES next.
//   X<=50us -> cold-latency/issue-bound load phase -> pipeline/stage next.
//   127-X   -> step+exchange cost (tests the ~10us estimate).
//
// Geometry (= v4, proven clean: 84 VGPR, no spill): 1024 blocks = 4/plane,
// 512 threads, 48-row window (32 owned + 8 halo each side), 3 rows x 4 cols
// per thread, weights in regs (fp16), two-barrier exchange, LDS 16KB.

constexpr int H = 128, W = 128, PLANE = H * W;
constexpr int NSTEP = 8;
constexpr int RPT  = 3;            // rows per thread (48-row window / 16 rg)
constexpr int NRG  = 16;
constexpr int HALO = 8;
constexpr int OWN  = 32;           // owned rows per block (4 blocks/plane)

// 6-wide column window (cols j0-1 .. j0+4) from a float4 row segment
#define MKWIN(D, V) do {                                                     \
    (D)[1] = (V).x; (D)[2] = (V).y; (D)[3] = (V).z; (D)[4] = (V).w;          \
    float _l = __shfl_up((V).w, 1);                                          \
    float _r = __shfl_down((V).x, 1);                                        \
    (D)[0] = (quad == 0)  ? 0.f : _l;                                        \
    (D)[5] = (quad == 31) ? 0.f : _r;                                        \
} while (0)

__global__ __launch_bounds__(512)
void diff_fused(const float* __restrict__ xin,
                const float* __restrict__ wgt,
                float* __restrict__ out)
{
    __shared__ float ldsT[NRG][W];      // each rg's top row    (8 KB)
    __shared__ float ldsB[NRG][W];      // each rg's bottom row (8 KB)

    const int tid   = threadIdx.x;
    const int quad  = tid & 31;         // cols 4q..4q+3
    const int rg    = tid >> 5;         // 0..15
    const int j0    = quad * 4;
    const int plane = blockIdx.x >> 2;
    const int qtr   = blockIdx.x & 3;
    const int rbase = qtr * OWN - HALO;         // window start row
    const int r0    = rbase + rg * RPT;         // this thread's first row
    const size_t pbase = (size_t)plane * PLANE;

    const float* __restrict__ xp = xin + pbase;
    const float* __restrict__ wb = wgt + pbase * 9;

    // ---- weight phase, executed TWICE for attribution ----
    __half2 wh[RPT][9][2];              // 54 VGPRs
    #pragma unroll 1
    for (int pass = 0; pass < 2; ++pass) {
        #pragma unroll
        for (int p = 0; p < RPT; ++p) {
            const int  gr  = r0 + p;
            const bool inr = (unsigned)gr < (unsigned)H;
            const float* wr = wb + gr * W + j0;
            float a[9][4];
            float s0 = 0.f, s1 = 0.f, s2 = 0.f, s3 = 0.f;
            #pragma unroll
            for (int k = 0; k < 9; ++k) {
                float4 v = make_float4(1.f, 1.f, 1.f, 1.f);  // dummy for pad rows
                if (inr) v = *reinterpret_cast<const float4*>(wr + (size_t)k * PLANE);
                a[k][0] = fabsf(v.x); a[k][1] = fabsf(v.y);
                a[k][2] = fabsf(v.z); a[k][3] = fabsf(v.w);
                s0 += a[k][0]; s1 += a[k][1]; s2 += a[k][2]; s3 += a[k][3];
            }
            s0 = 1.f / s0; s1 = 1.f / s1; s2 = 1.f / s2; s3 = 1.f / s3;
            #pragma unroll
            for (int k = 0; k < 9; ++k) {
                wh[p][k][0] = __halves2half2(__float2half_rn(a[k][0] * s0),
                                             __float2half_rn(a[k][1] * s1));
                wh[p][k][1] = __halves2half2(__float2half_rn(a[k][2] * s2),
                                             __float2half_rn(a[k][3] * s3));
            }
        }
        // pin this pass's results (keeps pass-1 dataflow alive, rule #17)
        #pragma unroll
        for (int p = 0; p < RPT; ++p) {
            #pragma unroll
            for (int k = 0; k < 9; ++k) {
                asm volatile("" :: "v"(__builtin_bit_cast(unsigned int, wh[p][k][0])));
                asm volatile("" :: "v"(__builtin_bit_cast(unsigned int, wh[p][k][1])));
            }
        }
        // forbid load CSE across passes
        asm volatile("" ::: "memory");
    }

    // ---- x window into registers (pad rows -> 0) ----
    float4 xr[RPT];
    #pragma unroll
    for (int p = 0; p < RPT; ++p) {
        const int gr = r0 + p;
        xr[p] = make_float4(0.f, 0.f, 0.f, 0.f);
        if ((unsigned)gr < (unsigned)H)
            xr[p] = *reinterpret_cast<const float4*>(xp + gr * W + j0);
    }

    // ---- 8 fused steps, zero global traffic, two barriers/step ----
    #pragma unroll 1
    for (int s = 0; s < NSTEP; ++s) {
        *reinterpret_cast<float4*>(&ldsT[rg][j0]) = xr[0];
        *reinterpret_cast<float4*>(&ldsB[rg][j0]) = xr[RPT - 1];
        __syncthreads();
        float4 up = make_float4(0.f, 0.f, 0.f, 0.f);   // row r0-1
        float4 dn = make_float4(0.f, 0.f, 0.f, 0.f);   // row r0+3
        if (rg > 0)       up = *reinterpret_cast<const float4*>(&ldsB[rg - 1][j0]);
        if (rg < NRG - 1) dn = *reinterpret_cast<const float4*>(&ldsT[rg + 1][j0]);
        __syncthreads();   // reads done before next step's writes

        float win[3][6];
        MKWIN(win[0], up);       // input row r0-1
        MKWIN(win[1], xr[0]);    // input row r0
        #pragma unroll
        for (int p = 0; p < RPT; ++p) {
            if (p < RPT - 1) { MKWIN(win[(p + 2) % 3], xr[p + 1]); }
            else             { MKWIN(win[(p + 2) % 3], dn); }
            float a0 = 0.f, a1 = 0.f, a2 = 0.f, a3 = 0.f;
            #pragma unroll
            for (int di = 0; di < 3; ++di) {
                #pragma unroll
                for (int dj = 0; dj < 3; ++dj) {
                    const int k = di * 3 + dj;
                    const __half2 w0 = wh[p][k][0];
                    const __half2 w1 = wh[p][k][1];
                    a0 = fmaf(__low2float (w0), win[(p + di) % 3][dj + 0], a0);
                    a1 = fmaf(__high2float(w0), win[(p + di) % 3][dj + 1], a1);
                    a2 = fmaf(__low2float (w1), win[(p + di) % 3][dj + 2], a2);
                    a3 = fmaf(__high2float(w1), win[(p + di) % 3][dj + 3], a3);
                }
            }
            xr[p] = make_float4(a0, a1, a2, a3);
        }
        // re-impose zero padding (keeps pad rows 0 every step)
        #pragma unroll
        for (int p = 0; p < RPT; ++p) {
            const int gr = r0 + p;
            if ((unsigned)gr >= (unsigned)H)
                xr[p] = make_float4(0.f, 0.f, 0.f, 0.f);
        }
    }

    // ---- store owned rows only (coalesced float4) ----
    float* __restrict__ op = out + pbase;
    #pragma unroll
    for (int p = 0; p < RPT; ++p) {
        const int gr = r0 + p;
        const int lr = gr - rbase - HALO;
        if ((unsigned)lr < (unsigned)OWN)
            *reinterpret_cast<float4*>(op + gr * W + j0) = xr[p];
    }
}

extern "C" void kernel_launch(void* const* d_in, const int* in_sizes, int n_in,
                              void* d_out, int out_size, void* d_ws, size_t ws_size,
                              hipStream_t stream)
{
    const float* x = (const float*)d_in[0];
    const float* w = (const float*)d_in[1];
    float* out = (float*)d_out;
    (void)d_ws; (void)ws_size; (void)in_sizes; (void)n_in; (void)out_size;

    // 1024 blocks = 4 per plane (4n x 64c), 512 threads
    diff_fused<<<dim3(4 * 4 * 64), dim3(512), 0, stream>>>(x, w, out);
}

// Round 7
// 247.270 us; speedup vs baseline: 1.5642x; 1.2920x over previous
//
#include <hip/hip_runtime.h>
#include <hip/hip_fp16.h>

// Fused 8-step diffusion, v8: concurrency-maximized load phase.
//
// v7 attribution: load phase = ~90us of v4's 127 (92% memory stall), step
// phase = ~35us. The SAME pattern re-issued warm runs 2.7x faster (33.6us)
// -> cold phase is LATENCY-bound under a small in-flight budget, not a BW
// wall. Cause: v4's p-outer/k-inner loop serializes on the sum|w| reduction
// every 9 loads (vmcnt drain + pack window issues nothing).
//
// v8 changes vs v4 (geometry/step loop identical):
//  1. k-outer UNNORMALIZED pack (v5 arithmetic, first un-spilled run): all
//     27 weight loads independent; |w| packed fp16 as each arrives, fp32
//     sums on the side, register-only normalize post-pass. No drain points.
//  2. x loads hoisted to the top (3 extra misses in flight).
//  3. XCD-chunked bijective block swizzle (1024%8==0): 4 quarters of each
//     plane + 32 consecutive planes per XCD -> quarter-halo re-reads hit
//     local L2.
//
// Geometry (= v4, proven clean): 1024 blocks = 4/plane, 512 threads, 48-row
// window (32 owned + 8 halo each side), 3 rows x 4 cols/thread, weights in
// regs (fp16), two-barrier exchange (v3's single-barrier raced), LDS 16KB,
// plain __launch_bounds__(512) (the only shape that yields a >64 VGPR cap).

constexpr int H = 128, W = 128, PLANE = H * W;
constexpr int NSTEP = 8;
constexpr int RPT  = 3;            // rows per thread (48-row window / 16 rg)
constexpr int NRG  = 16;
constexpr int HALO = 8;
constexpr int OWN  = 32;           // owned rows per block (4 blocks/plane)

// 6-wide column window (cols j0-1 .. j0+4) from a float4 row segment
#define MKWIN(D, V) do {                                                     \
    (D)[1] = (V).x; (D)[2] = (V).y; (D)[3] = (V).z; (D)[4] = (V).w;          \
    float _l = __shfl_up((V).w, 1);                                          \
    float _r = __shfl_down((V).x, 1);                                        \
    (D)[0] = (quad == 0)  ? 0.f : _l;                                        \
    (D)[5] = (quad == 31) ? 0.f : _r;                                        \
} while (0)

__global__ __launch_bounds__(512)
void diff_fused(const float* __restrict__ xin,
                const float* __restrict__ wgt,
                float* __restrict__ out)
{
    __shared__ float ldsT[NRG][W];      // each rg's top row    (8 KB)
    __shared__ float ldsB[NRG][W];      // each rg's bottom row (8 KB)

    const int tid   = threadIdx.x;
    const int quad  = tid & 31;         // cols 4q..4q+3
    const int rg    = tid >> 5;         // 0..15
    const int j0    = quad * 4;

    // XCD-chunked swizzle: hw block i -> logical (i&7)*128 + (i>>3).
    // XCD k (hw i%8==k) gets logical 128k..128k+127 = planes 32k..32k+31,
    // all 4 quarters of each -> halo re-reads are XCD-local.
    const int lb    = (blockIdx.x & 7) * 128 + (blockIdx.x >> 3);
    const int plane = lb >> 2;
    const int qtr   = lb & 3;
    const int rbase = qtr * OWN - HALO;         // window start row
    const int r0    = rbase + rg * RPT;         // this thread's first row
    const size_t pbase = (size_t)plane * PLANE;

    const float* __restrict__ xp = xin + pbase;
    const float* __restrict__ wb = wgt + pbase * 9;

    // ---- x window first: 3 independent misses in flight early ----
    float4 xr[RPT];
    #pragma unroll
    for (int p = 0; p < RPT; ++p) {
        const int gr = r0 + p;
        xr[p] = make_float4(0.f, 0.f, 0.f, 0.f);
        if ((unsigned)gr < (unsigned)H)
            xr[p] = *reinterpret_cast<const float4*>(xp + gr * W + j0);
    }

    // ---- weights: k-outer, pack |.| fp16 UNNORMALIZED as loads arrive,
    //      fp32 sums on the side; register-only normalize post-pass.
    //      All 27 loads sum-independent -> deep miss pipeline. ----
    __half2 wh[RPT][9][2];              // 54 VGPRs
    float s[RPT][4];
    #pragma unroll
    for (int p = 0; p < RPT; ++p) { s[p][0] = s[p][1] = s[p][2] = s[p][3] = 0.f; }

    #pragma unroll
    for (int k = 0; k < 9; ++k) {
        float4 v[RPT];
        #pragma unroll
        for (int p = 0; p < RPT; ++p) {
            const int gr = r0 + p;
            v[p] = make_float4(1.f, 1.f, 1.f, 1.f);      // dummy for pad rows
            if ((unsigned)gr < (unsigned)H)
                v[p] = *reinterpret_cast<const float4*>(
                           wb + (size_t)k * PLANE + gr * W + j0);
        }
        #pragma unroll
        for (int p = 0; p < RPT; ++p) {
            const float a0 = fabsf(v[p].x), a1 = fabsf(v[p].y);
            const float a2 = fabsf(v[p].z), a3 = fabsf(v[p].w);
            s[p][0] += a0; s[p][1] += a1; s[p][2] += a2; s[p][3] += a3;
            wh[p][k][0] = __halves2half2(__float2half_rn(a0), __float2half_rn(a1));
            wh[p][k][1] = __halves2half2(__float2half_rn(a2), __float2half_rn(a3));
        }
    }
    // normalize post-pass (register-only)
    #pragma unroll
    for (int p = 0; p < RPT; ++p) {
        const float i0 = 1.f / s[p][0], i1 = 1.f / s[p][1];
        const float i2 = 1.f / s[p][2], i3 = 1.f / s[p][3];
        #pragma unroll
        for (int k = 0; k < 9; ++k) {
            wh[p][k][0] = __halves2half2(
                __float2half_rn(__low2float (wh[p][k][0]) * i0),
                __float2half_rn(__high2float(wh[p][k][0]) * i1));
            wh[p][k][1] = __halves2half2(
                __float2half_rn(__low2float (wh[p][k][1]) * i2),
                __float2half_rn(__high2float(wh[p][k][1]) * i3));
        }
    }

    // ---- 8 fused steps, zero global traffic, two barriers/step ----
    #pragma unroll 1
    for (int st = 0; st < NSTEP; ++st) {
        *reinterpret_cast<float4*>(&ldsT[rg][j0]) = xr[0];
        *reinterpret_cast<float4*>(&ldsB[rg][j0]) = xr[RPT - 1];
        __syncthreads();
        float4 up = make_float4(0.f, 0.f, 0.f, 0.f);   // row r0-1
        float4 dn = make_float4(0.f, 0.f, 0.f, 0.f);   // row r0+3
        if (rg > 0)       up = *reinterpret_cast<const float4*>(&ldsB[rg - 1][j0]);
        if (rg < NRG - 1) dn = *reinterpret_cast<const float4*>(&ldsT[rg + 1][j0]);
        __syncthreads();   // reads done before next step's writes

        float win[3][6];
        MKWIN(win[0], up);       // input row r0-1
        MKWIN(win[1], xr[0]);    // input row r0
        #pragma unroll
        for (int p = 0; p < RPT; ++p) {
            if (p < RPT - 1) { MKWIN(win[(p + 2) % 3], xr[p + 1]); }
            else             { MKWIN(win[(p + 2) % 3], dn); }
            float a0 = 0.f, a1 = 0.f, a2 = 0.f, a3 = 0.f;
            #pragma unroll
            for (int di = 0; di < 3; ++di) {
                #pragma unroll
                for (int dj = 0; dj < 3; ++dj) {
                    const int k = di * 3 + dj;
                    const __half2 w0 = wh[p][k][0];
                    const __half2 w1 = wh[p][k][1];
                    a0 = fmaf(__low2float (w0), win[(p + di) % 3][dj + 0], a0);
                    a1 = fmaf(__high2float(w0), win[(p + di) % 3][dj + 1], a1);
                    a2 = fmaf(__low2float (w1), win[(p + di) % 3][dj + 2], a2);
                    a3 = fmaf(__high2float(w1), win[(p + di) % 3][dj + 3], a3);
                }
            }
            xr[p] = make_float4(a0, a1, a2, a3);
        }
        // re-impose zero padding (keeps pad rows 0 every step)
        #pragma unroll
        for (int p = 0; p < RPT; ++p) {
            const int gr = r0 + p;
            if ((unsigned)gr >= (unsigned)H)
                xr[p] = make_float4(0.f, 0.f, 0.f, 0.f);
        }
    }

    // ---- store owned rows only (coalesced float4) ----
    float* __restrict__ op = out + pbase;
    #pragma unroll
    for (int p = 0; p < RPT; ++p) {
        const int gr = r0 + p;
        const int lr = gr - rbase - HALO;
        if ((unsigned)lr < (unsigned)OWN)
            *reinterpret_cast<float4*>(op + gr * W + j0) = xr[p];
    }
}

extern "C" void kernel_launch(void* const* d_in, const int* in_sizes, int n_in,
                              void* d_out, int out_size, void* d_ws, size_t ws_size,
                              hipStream_t stream)
{
    const float* x = (const float*)d_in[0];
    const float* w = (const float*)d_in[1];
    float* out = (float*)d_out;
    (void)d_ws; (void)ws_size; (void)in_sizes; (void)n_in; (void)out_size;

    // 1024 blocks = 4 per plane (4n x 64c), 512 threads
    diff_fused<<<dim3(4 * 4 * 64), dim3(512), 0, stream>>>(x, w, out);
}